// Round 6
// baseline (3209.891 us; speedup 1.0000x reference)
//
#include <hip/hip_runtime.h>
#include <stdint.h>
#include <stdio.h>

typedef __attribute__((ext_vector_type(8))) short short8;
typedef __attribute__((ext_vector_type(4))) float f32x4;
typedef __attribute__((ext_vector_type(4))) unsigned int u32x4;

#define DEV static __device__ __forceinline__

DEV unsigned short f2bf(float f){
  unsigned u = __float_as_uint(f);
  u += 0x7FFFu + ((u >> 16) & 1u);          // RNE
  return (unsigned short)(u >> 16);
}
DEV float bf2f(unsigned short h){ return __uint_as_float(((unsigned)h) << 16); }

// ---------------------------------------------------------------------------
// x (8,96,256,256) f32  ->  xt (8,260,260,128) bf16 channels-last with halo=2
// ---------------------------------------------------------------------------
__global__ __launch_bounds__(256) void k_xt(const float* __restrict__ x,
                                            unsigned short* __restrict__ xt){
  int bid = blockIdx.x;                 // 8*256*4
  int wq = bid & 3, h = (bid >> 2) & 255, b = bid >> 10;
  int w0 = wq * 64;
  __shared__ unsigned short s[64 * 104];
  int t = threadIdx.x;
  int wl = t & 63, cq = t >> 6;         // cq 0..3
  const float* xp = x + ((size_t)b * 96 * 256 + h) * 256 + w0 + wl;
  #pragma unroll
  for (int i = 0; i < 24; ++i){
    int c = cq + i * 4;                 // 0..95
    s[wl * 104 + c] = f2bf(xp[(size_t)c * 65536]);
  }
  __syncthreads();
  unsigned short* dst = xt + (((size_t)b * 260 + h + 2) * 260 + (w0 + 2)) * 128;
  #pragma unroll
  for (int p = 0; p < 3; ++p){
    int i = t + p * 256;                // 0..767 = 64 w * 12 chunks
    int w = i / 12, ch = i % 12;
    u32x4 v = *(const u32x4*)&s[w * 104 + ch * 8];
    *(u32x4*)&dst[(size_t)w * 128 + ch * 8] = v;
  }
}

// ---------------------------------------------------------------------------
// weight repack (bf16):
//  A2  [768][ (kh*5+kw)*96 + ic ]   patch-conv weights (r then c)
//  Aun [m=co*4+p*2+q][ci 0..767]    unpatch weights
//  Agr [side][m 0..191][k 0..95]    gru weights transposed
//  bun [96] f32 = r_un_b + c_un_b
// ---------------------------------------------------------------------------
__global__ __launch_bounds__(256) void k_pack(const float* __restrict__ rpw, const float* __restrict__ cpw,
    const float* __restrict__ runw, const float* __restrict__ cunw,
    const float* __restrict__ runb, const float* __restrict__ cunb,
    const float* __restrict__ rgw,  const float* __restrict__ cgw,
    unsigned short* __restrict__ A2, unsigned short* __restrict__ Aun,
    unsigned short* __restrict__ Agr, float* __restrict__ bun){
  int tid = blockIdx.x * 256 + threadIdx.x;
  const int NA2 = 768 * 2400, NUN = 384 * 768, NGR = 2 * 192 * 96;
  if (tid < NA2){
    int oc = tid / 2400, r = tid % 2400;
    int kh = r / 480, kw = (r / 96) % 5, ic = r % 96;
    const float* W = oc < 384 ? rpw : cpw;
    int o = oc < 384 ? oc : oc - 384;
    A2[tid] = f2bf(W[(((size_t)o * 96 + ic) * 5 + kh) * 5 + kw]);
  } else if (tid < NA2 + NUN){
    int i = tid - NA2;
    int m = i / 768, ci = i % 768;
    int co = m >> 2, p = (m >> 1) & 1, q = m & 1;
    const float* W = ci < 384 ? runw : cunw;
    int c = ci < 384 ? ci : ci - 384;
    Aun[i] = f2bf(W[(((size_t)c * 96 + co) * 2 + p) * 2 + q]);
  } else if (tid < NA2 + NUN + NGR){
    int i = tid - NA2 - NUN;
    int side = i / 18432, r = i % 18432;
    int m = r / 96, k = r % 96;
    const float* W = side ? cgw : rgw;       // (96,192) row-major
    Agr[i] = f2bf(W[k * 192 + m]);
  } else if (tid < NA2 + NUN + NGR + 96){
    int co = tid - NA2 - NUN - NGR;
    bun[co] = runb[co] + cunb[co];
  }
}

// ---------------------------------------------------------------------------
// patch conv as implicit GEMM, v2.
// Block: 128 oc x 128 px (4 ho x 32 wo), 4 waves = 2mw x 2nw,
// wave tile = 64 oc x 64 px (4 ho x 16 wo), acc[4 mf][4 hol].
// B staged per kh into LDS: [4 rows][67 cols][16 chunks x 16B] = 68608 B,
// chunk-swizzled phys = ch ^ ((col>>1)&7).  A-fragments read DIRECTLY from
// global (A2 is L1/L2-hot: 24.6 KB per (kh,kw) slab) -> no A LDS, no A
// barrier; only 2 barriers per kh.
// ---------------------------------------------------------------------------
__global__ __launch_bounds__(256) void k_conv(const unsigned short* __restrict__ xt,
    const unsigned short* __restrict__ A2,
    const float* __restrict__ rpb, const float* __restrict__ cpb,
    unsigned short* __restrict__ pm, unsigned short* __restrict__ cl){
  __shared__ char lds[68608];
  int t = threadIdx.x, lane = t & 63;
  int wid = t >> 6, mw = wid >> 1, nw = wid & 1;
  int nt = blockIdx.x;                 // 1024 = b(8) * hq(32) * wq(4)
  int wq = nt & 3, hq = (nt >> 2) & 31, b = nt >> 7;
  int ho0 = hq * 4, wo0 = wq * 32;
  int M0 = blockIdx.y * 128;

  // per-thread A base: row = M0 + mw*64 + (lane&15), k-chunk = (lane>>4)*8
  const unsigned short* Abase = A2 + (size_t)(M0 + mw * 64 + (lane & 15)) * 2400 + (lane >> 4) * 8;

  f32x4 acc[4][4];
  #pragma unroll
  for (int i = 0; i < 4; ++i)
    #pragma unroll
    for (int j = 0; j < 4; ++j) acc[i][j] = (f32x4){0.f, 0.f, 0.f, 0.f};

  for (int kh = 0; kh < 5; ++kh){
    __syncthreads();
    // stage B: 4 rows x 67 cols x 16 chunks (4288 items of 16B)
    for (int it = 0; it < 17; ++it){
      int i = t + it * 256;
      if (i < 4288){
        int row = i / 1072, j = i % 1072;
        int col = j >> 4, ch = j & 15;
        size_t src = (((size_t)b * 260 + (2 * ho0 + 2 * row + kh)) * 260 + 2 * wo0 + col) * 128 + ch * 8;
        u32x4 v = *(const u32x4*)&xt[src];
        int chs = ch ^ ((col >> 1) & 7);
        *(u32x4*)(lds + row * 17152 + col * 256 + chs * 16) = v;
      }
    }
    __syncthreads();
    const unsigned short* Akh = Abase + kh * 480;   // + kh*5*96
    #pragma unroll
    for (int kw = 0; kw < 5; ++kw){
      #pragma unroll
      for (int ics = 0; ics < 3; ++ics){
        short8 af[4], bfr[4];
        #pragma unroll
        for (int mf = 0; mf < 4; ++mf)
          af[mf] = *(const short8*)(Akh + (size_t)mf * 16 * 2400 + kw * 96 + ics * 32);
        int col = 32 * nw + 2 * (lane & 15) + kw;
        int chl = (ics * 4 + (lane >> 4)) ^ ((col >> 1) & 7);
        #pragma unroll
        for (int nf = 0; nf < 4; ++nf)
          bfr[nf] = *(const short8*)(lds + nf * 17152 + col * 256 + chl * 16);
        #pragma unroll
        for (int mf = 0; mf < 4; ++mf)
          #pragma unroll
          for (int nf = 0; nf < 4; ++nf)
            acc[mf][nf] = __builtin_amdgcn_mfma_f32_16x16x32_bf16(af[mf], bfr[nf], acc[mf][nf], 0, 0, 0);
      }
    }
  }
  // epilogue: bias, plane-major write, channels-last cooperative write
  __syncthreads();
  unsigned short* S = (unsigned short*)lds;   // [128 px][128 oc] = 32768 B
  #pragma unroll
  for (int mf = 0; mf < 4; ++mf)
    #pragma unroll
    for (int nf = 0; nf < 4; ++nf){
      int hol = nf, wol = nw * 16 + (lane & 15);
      int ho = ho0 + hol, wo = wo0 + wol;
      #pragma unroll
      for (int j = 0; j < 4; ++j){
        int oc = M0 + mw * 64 + mf * 16 + (lane >> 4) * 4 + j;
        float v = acc[mf][nf][j] + (oc < 384 ? rpb[oc] : cpb[oc - 384]);
        unsigned short hbits = f2bf(v);
        pm[(((size_t)b * 768 + oc) * 128 + ho) * 128 + wo] = hbits;
        S[(hol * 32 + wol) * 128 + (oc - M0)] = hbits;
      }
    }
  __syncthreads();
  #pragma unroll
  for (int it = 0; it < 8; ++it){
    int i = t + it * 256;               // 0..2047 = 128 px * 16 chunks
    int pxl = i >> 4, ch = i & 15;
    int ho = ho0 + (pxl >> 5), wo = wo0 + (pxl & 31);
    u32x4 v = *(const u32x4*)&S[pxl * 128 + ch * 8];
    *(u32x4*)&cl[(((size_t)b * 128 + ho) * 128 + wo) * 768 + M0 + ch * 8] = v;
  }
}

// ---------------------------------------------------------------------------
// positional grouped conv 3x3 (validated round 4).
// ---------------------------------------------------------------------------
__global__ __launch_bounds__(256) void k_pe(const unsigned short* __restrict__ pm,
    const float* __restrict__ rpew, const float* __restrict__ cpew,
    const float* __restrict__ rpeb, const float* __restrict__ cpeb,
    unsigned short* __restrict__ sum){
  __shared__ unsigned short si[48 * 340];  // [48 ch][10 r][34 c]
  __shared__ float sw[48 * 36];
  __shared__ float sb[48];
  int bid = blockIdx.x;                    // 8*16*16*4
  int wq = bid & 3, hq = (bid >> 2) & 15, slab = (bid >> 6) & 15, b = bid >> 10;
  int ch0 = slab * 48, hp0 = hq * 8, wp0 = wq * 32;
  int t = threadIdx.x;
  for (int i = t; i < 48 * 36; i += 256){
    int ocl = i / 36, r = i % 36;
    int oc = ch0 + ocl;
    const float* W = oc < 384 ? rpew : cpew;
    int o = oc < 384 ? oc : oc - 384;
    sw[i] = W[(size_t)o * 36 + r];
  }
  if (t < 48){
    int oc = ch0 + t;
    sb[t] = oc < 384 ? rpeb[oc] : cpeb[oc - 384];
  }
  for (int i = t; i < 48 * 340; i += 256){
    int c = i / 340, r2 = (i % 340) / 34, cc = i % 34;
    int hp = hp0 - 1 + r2, wp = wp0 - 1 + cc;
    unsigned short v = 0;
    if (hp >= 0 && hp < 128 && wp >= 0 && wp < 128)
      v = pm[(((size_t)b * 768 + ch0 + c) * 128 + hp) * 128 + wp];
    si[i] = v;
  }
  __syncthreads();
  int hpl = t >> 5, wpl = t & 31;
  unsigned int outp[24];
  #pragma unroll
  for (int g = 0; g < 12; ++g){
    float win[36];
    #pragma unroll
    for (int ii = 0; ii < 4; ++ii)
      #pragma unroll
      for (int dh = 0; dh < 3; ++dh)
        #pragma unroll
        for (int dw = 0; dw < 3; ++dw)
          win[ii * 9 + dh * 3 + dw] = bf2f(si[(g * 4 + ii) * 340 + (hpl + dh) * 34 + (wpl + dw)]);
    float o[4];
    #pragma unroll
    for (int ol = 0; ol < 4; ++ol){
      int ocl = g * 4 + ol;
      float a = sb[ocl];
      const float* wp_ = &sw[ocl * 36];
      #pragma unroll
      for (int u = 0; u < 36; ++u) a = fmaf(wp_[u], win[u], a);
      o[ol] = a;
    }
    outp[g * 2]     = (unsigned)f2bf(o[0]) | ((unsigned)f2bf(o[1]) << 16);
    outp[g * 2 + 1] = (unsigned)f2bf(o[2]) | ((unsigned)f2bf(o[3]) << 16);
  }
  size_t obase = (((size_t)b * 128 + hp0 + hpl) * 128 + wp0 + wpl) * 768 + ch0;
  #pragma unroll
  for (int c6 = 0; c6 < 6; ++c6){
    u32x4 v = { outp[c6 * 4], outp[c6 * 4 + 1], outp[c6 * 4 + 2], outp[c6 * 4 + 3] };
    *(u32x4*)&sum[obase + c6 * 8] = v;
  }
}

// ---------------------------------------------------------------------------
// hg GEMM (one side per launch), validated round 5.
// ---------------------------------------------------------------------------
__global__ __launch_bounds__(256) void k_hg(const unsigned short* __restrict__ cl,
    const unsigned short* __restrict__ Agr, unsigned short* __restrict__ hg,
    int side){
  __shared__ char lds[46592];             // A [96][208B]=19968 | B [128][208B]
  int t = threadIdx.x, lane = t & 63, wid = t >> 6;
  int head = blockIdx.z;
  int M0 = blockIdx.y * 96;
  size_t N0 = (size_t)blockIdx.x * 128;
  for (int i = t; i < 1152; i += 256){
    int m = i / 12, c = i % 12;
    u32x4 v = *(const u32x4*)&Agr[((size_t)side * 192 + M0 + m) * 96 + c * 8];
    *(u32x4*)(lds + m * 208 + c * 16) = v;
  }
  for (int i = t; i < 1536; i += 256){
    int px = i / 12, c = i % 12;
    u32x4 v = *(const u32x4*)&cl[(N0 + px) * 768 + side * 384 + head * 96 + c * 8];
    *(u32x4*)(lds + 19968 + px * 208 + c * 16) = v;
  }
  __syncthreads();
  f32x4 acc[6][2];
  #pragma unroll
  for (int i = 0; i < 6; ++i)
    #pragma unroll
    for (int j = 0; j < 2; ++j) acc[i][j] = (f32x4){0.f, 0.f, 0.f, 0.f};
  #pragma unroll
  for (int ks = 0; ks < 3; ++ks){
    short8 af[6], bfr[2];
    #pragma unroll
    for (int mf = 0; mf < 6; ++mf)
      af[mf] = *(const short8*)(lds + (mf * 16 + (lane & 15)) * 208 + ks * 64 + (lane >> 4) * 16);
    #pragma unroll
    for (int nf = 0; nf < 2; ++nf)
      bfr[nf] = *(const short8*)(lds + 19968 + (wid * 32 + nf * 16 + (lane & 15)) * 208 + ks * 64 + (lane >> 4) * 16);
    #pragma unroll
    for (int mf = 0; mf < 6; ++mf)
      #pragma unroll
      for (int nf = 0; nf < 2; ++nf)
        acc[mf][nf] = __builtin_amdgcn_mfma_f32_16x16x32_bf16(af[mf], bfr[nf], acc[mf][nf], 0, 0, 0);
  }
  #pragma unroll
  for (int mf = 0; mf < 6; ++mf)
    #pragma unroll
    for (int nf = 0; nf < 2; ++nf){
      int m = M0 + mf * 16 + ((lane >> 4) << 2);
      size_t px = N0 + wid * 32 + nf * 16 + (lane & 15);
      int b = (int)(px >> 14); size_t pxl = px & 16383;
      size_t base = (((size_t)b * 4 + head) * 16384 + pxl) * 192 + m;
      unsigned p0 = (unsigned)f2bf(acc[mf][nf][0]) | ((unsigned)f2bf(acc[mf][nf][1]) << 16);
      unsigned p1 = (unsigned)f2bf(acc[mf][nf][2]) | ((unsigned)f2bf(acc[mf][nf][3]) << 16);
      unsigned long long pp = (unsigned long long)p0 | ((unsigned long long)p1 << 32);
      *(unsigned long long*)&hg[base] = pp;
    }
}

// ---------------------------------------------------------------------------
// minGRU recurrence (one side per launch), validated round 5.
// ---------------------------------------------------------------------------
__global__ __launch_bounds__(192) void k_scan2(const unsigned short* __restrict__ hg,
                                               unsigned short* __restrict__ sum,
                                               int side){
  int bid = blockIdx.x;
  int xq = bid & 63, head = (bid >> 6) & 3, b = bid >> 8;
  int t = threadIdx.x;
  int d = t % 96, xl = t / 96;
  int x = xq * 2 + xl;
  const unsigned short* hb = &hg[(((size_t)b * 4 + head) * 16384) * 192];
  float h = 0.f;
  for (int step = 0; step < 128; ++step){
    int pxl = side ? (x * 128 + step) : (step * 128 + x);
    float hid = bf2f(hb[(size_t)pxl * 192 + d]);
    float gat = bf2f(hb[(size_t)pxl * 192 + 96 + d]);
    float z  = 1.f / (1.f + __expf(-gat));
    float th = hid >= 0.f ? hid + 0.5f : 1.f / (1.f + __expf(-hid));
    h += z * (th - h);
    size_t o = ((size_t)b * 16384 + pxl) * 768 + side * 384 + head * 96 + d;
    sum[o] = f2bf(bf2f(sum[o]) + h);
  }
}

// ---------------------------------------------------------------------------
// unpatch (validated round 4).
// ---------------------------------------------------------------------------
__global__ __launch_bounds__(256) void k_unpatch(const unsigned short* __restrict__ sum,
    const unsigned short* __restrict__ Aun, const float* __restrict__ bun,
    float* __restrict__ out){
  __shared__ char lds[53248];            // A [128][208B] | B [128][208B]
  int t = threadIdx.x, lane = t & 63;
  int wid = t >> 6, mw = wid >> 1, nw = wid & 1;
  int M0 = blockIdx.y * 128;
  size_t N0 = (size_t)blockIdx.x * 128;
  f32x4 acc[4][4];
  #pragma unroll
  for (int i = 0; i < 4; ++i)
    #pragma unroll
    for (int j = 0; j < 4; ++j) acc[i][j] = (f32x4){0.f, 0.f, 0.f, 0.f};
  for (int kc = 0; kc < 8; ++kc){
    __syncthreads();
    for (int i = t; i < 1536; i += 256){
      int m = i / 12, c = i % 12;
      u32x4 v = *(const u32x4*)&Aun[(size_t)(M0 + m) * 768 + kc * 96 + c * 8];
      *(u32x4*)(lds + m * 208 + c * 16) = v;
    }
    for (int i = t; i < 1536; i += 256){
      int px = i / 12, c = i % 12;
      u32x4 v = *(const u32x4*)&sum[(N0 + px) * 768 + kc * 96 + c * 8];
      *(u32x4*)(lds + 26624 + px * 208 + c * 16) = v;
    }
    __syncthreads();
    #pragma unroll
    for (int ks = 0; ks < 3; ++ks){
      short8 af[4], bfr[4];
      #pragma unroll
      for (int mf = 0; mf < 4; ++mf)
        af[mf] = *(const short8*)(lds + (mw * 64 + mf * 16 + (lane & 15)) * 208 + ks * 64 + (lane >> 4) * 16);
      #pragma unroll
      for (int nf = 0; nf < 4; ++nf)
        bfr[nf] = *(const short8*)(lds + 26624 + (nw * 64 + nf * 16 + (lane & 15)) * 208 + ks * 64 + (lane >> 4) * 16);
      #pragma unroll
      for (int mf = 0; mf < 4; ++mf)
        #pragma unroll
        for (int nf = 0; nf < 4; ++nf)
          acc[mf][nf] = __builtin_amdgcn_mfma_f32_16x16x32_bf16(af[mf], bfr[nf], acc[mf][nf], 0, 0, 0);
    }
  }
  #pragma unroll
  for (int mf = 0; mf < 4; ++mf)
    #pragma unroll
    for (int nf = 0; nf < 4; ++nf)
      #pragma unroll
      for (int j = 0; j < 4; ++j){
        int m = M0 + mw * 64 + mf * 16 + (lane >> 4) * 4 + j;
        int co = m >> 2, p = (m >> 1) & 1, q = m & 1;
        size_t px = N0 + nw * 64 + nf * 16 + (lane & 15);
        int b = (int)(px >> 14); int pxl = (int)(px & 16383);
        int hp = pxl >> 7, wp = pxl & 127;
        out[(((size_t)b * 96 + co) * 256 + 2 * hp + p) * 256 + 2 * wp + q] = acc[mf][nf][j] + bun[co];
      }
}

// ---------------------------------------------------------------------------
extern "C" void kernel_launch(void* const* d_in, const int* in_sizes, int n_in,
                              void* d_out, int out_size, void* d_ws, size_t ws_size,
                              hipStream_t stream){
  (void)in_sizes; (void)n_in; (void)out_size;
  const float* x    = (const float*)d_in[0];
  const float* rpw  = (const float*)d_in[1];
  const float* rpb  = (const float*)d_in[2];
  const float* cpw  = (const float*)d_in[3];
  const float* cpb  = (const float*)d_in[4];
  const float* rpew = (const float*)d_in[5];
  const float* rpeb = (const float*)d_in[6];
  const float* cpew = (const float*)d_in[7];
  const float* cpeb = (const float*)d_in[8];
  const float* runw = (const float*)d_in[9];
  const float* runb = (const float*)d_in[10];
  const float* cunw = (const float*)d_in[11];
  const float* cunb = (const float*)d_in[12];
  const float* rgw  = (const float*)d_in[13];
  const float* cgw  = (const float*)d_in[14];

  char* ws = (char*)d_ws;
  const size_t SZ_XT   = (size_t)8 * 260 * 260 * 128 * 2;   // 138,444,800
  const size_t OFF_A2  = SZ_XT;
  const size_t SZ_A2   = (size_t)768 * 2400 * 2;
  const size_t OFF_AUN = OFF_A2 + SZ_A2;
  const size_t SZ_AUN  = (size_t)384 * 768 * 2;
  const size_t OFF_AGR = OFF_AUN + SZ_AUN;
  const size_t SZ_AGR  = (size_t)2 * 192 * 96 * 2;
  const size_t OFF_BUN = OFF_AGR + SZ_AGR;
  const size_t OFF_PM  = ((OFF_BUN + 384) + 255) & ~(size_t)255;
  const size_t SZ_PL   = (size_t)8 * 768 * 128 * 128 * 2;   // 201,326,592
  const size_t OFF_CL  = OFF_PM + SZ_PL;
  const size_t OFF_SUM = OFF_CL + SZ_PL;
  const size_t NEED    = OFF_SUM + SZ_PL;                   // ~747 MB
  if (ws_size < NEED){
    fprintf(stderr, "kernel_launch: ws_size %zu < needed %zu\n", ws_size, NEED);
    return;
  }
  unsigned short* xt  = (unsigned short*)(ws);
  unsigned short* A2  = (unsigned short*)(ws + OFF_A2);
  unsigned short* Aun = (unsigned short*)(ws + OFF_AUN);
  unsigned short* Agr = (unsigned short*)(ws + OFF_AGR);
  float*          bun = (float*)(ws + OFF_BUN);
  unsigned short* pm  = (unsigned short*)(ws + OFF_PM);
  unsigned short* hg  = pm;   // overlay: per-side hg (= SZ_PL exactly); pm dead after k_pe
  unsigned short* cl  = (unsigned short*)(ws + OFF_CL);
  unsigned short* sum = (unsigned short*)(ws + OFF_SUM);
  float* out = (float*)d_out;

  hipMemsetAsync(xt, 0, SZ_XT, stream);
  k_xt  <<<dim3(8192),       dim3(256), 0, stream>>>(x, xt);
  k_pack<<<dim3(8497),       dim3(256), 0, stream>>>(rpw, cpw, runw, cunw, runb, cunb, rgw, cgw, A2, Aun, Agr, bun);
  k_conv<<<dim3(1024, 6),    dim3(256), 0, stream>>>(xt, A2, rpb, cpb, pm, cl);
  k_pe  <<<dim3(8192),       dim3(256), 0, stream>>>(pm, rpew, cpew, rpeb, cpeb, sum);
  k_hg   <<<dim3(1024, 2, 4),dim3(256), 0, stream>>>(cl, Agr, hg, 0);
  k_scan2<<<dim3(2048),      dim3(192), 0, stream>>>(hg, sum, 0);
  k_hg   <<<dim3(1024, 2, 4),dim3(256), 0, stream>>>(cl, Agr, hg, 1);
  k_scan2<<<dim3(2048),      dim3(192), 0, stream>>>(hg, sum, 1);
  k_unpatch<<<dim3(1024, 3), dim3(256), 0, stream>>>(sum, Aun, bun, out);
}

// Round 7
// 2677.858 us; speedup vs baseline: 1.1987x; 1.1987x over previous
//
#include <hip/hip_runtime.h>
#include <stdint.h>
#include <stdio.h>

typedef __attribute__((ext_vector_type(8))) short short8;
typedef __attribute__((ext_vector_type(4))) float f32x4;
typedef __attribute__((ext_vector_type(4))) unsigned int u32x4;

#define DEV static __device__ __forceinline__

DEV unsigned short f2bf(float f){
  unsigned u = __float_as_uint(f);
  u += 0x7FFFu + ((u >> 16) & 1u);          // RNE
  return (unsigned short)(u >> 16);
}
DEV float bf2f(unsigned short h){ return __uint_as_float(((unsigned)h) << 16); }

// ---------------------------------------------------------------------------
// x (8,96,256,256) f32  ->  xt (8,260,260,128) bf16 channels-last with halo=2
// ---------------------------------------------------------------------------
__global__ __launch_bounds__(256) void k_xt(const float* __restrict__ x,
                                            unsigned short* __restrict__ xt){
  int bid = blockIdx.x;                 // 8*256*4
  int wq = bid & 3, h = (bid >> 2) & 255, b = bid >> 10;
  int w0 = wq * 64;
  __shared__ unsigned short s[64 * 104];
  int t = threadIdx.x;
  int wl = t & 63, cq = t >> 6;         // cq 0..3
  const float* xp = x + ((size_t)b * 96 * 256 + h) * 256 + w0 + wl;
  #pragma unroll
  for (int i = 0; i < 24; ++i){
    int c = cq + i * 4;                 // 0..95
    s[wl * 104 + c] = f2bf(xp[(size_t)c * 65536]);
  }
  __syncthreads();
  unsigned short* dst = xt + (((size_t)b * 260 + h + 2) * 260 + (w0 + 2)) * 128;
  #pragma unroll
  for (int p = 0; p < 3; ++p){
    int i = t + p * 256;                // 0..767 = 64 w * 12 chunks
    int w = i / 12, ch = i % 12;
    u32x4 v = *(const u32x4*)&s[w * 104 + ch * 8];
    *(u32x4*)&dst[(size_t)w * 128 + ch * 8] = v;
  }
}

// ---------------------------------------------------------------------------
// weight repack (bf16):
//  A2  [768][ (kh*5+kw)*96 + ic ]   patch-conv weights (r then c)
//  Aun [m=co*4+p*2+q][ci 0..767]    unpatch weights
//  Agr [side][m 0..191][k 0..95]    gru weights transposed
//  bun [96] f32 = r_un_b + c_un_b
// ---------------------------------------------------------------------------
__global__ __launch_bounds__(256) void k_pack(const float* __restrict__ rpw, const float* __restrict__ cpw,
    const float* __restrict__ runw, const float* __restrict__ cunw,
    const float* __restrict__ runb, const float* __restrict__ cunb,
    const float* __restrict__ rgw,  const float* __restrict__ cgw,
    unsigned short* __restrict__ A2, unsigned short* __restrict__ Aun,
    unsigned short* __restrict__ Agr, float* __restrict__ bun){
  int tid = blockIdx.x * 256 + threadIdx.x;
  const int NA2 = 768 * 2400, NUN = 384 * 768, NGR = 2 * 192 * 96;
  if (tid < NA2){
    int oc = tid / 2400, r = tid % 2400;
    int kh = r / 480, kw = (r / 96) % 5, ic = r % 96;
    const float* W = oc < 384 ? rpw : cpw;
    int o = oc < 384 ? oc : oc - 384;
    A2[tid] = f2bf(W[(((size_t)o * 96 + ic) * 5 + kh) * 5 + kw]);
  } else if (tid < NA2 + NUN){
    int i = tid - NA2;
    int m = i / 768, ci = i % 768;
    int co = m >> 2, p = (m >> 1) & 1, q = m & 1;
    const float* W = ci < 384 ? runw : cunw;
    int c = ci < 384 ? ci : ci - 384;
    Aun[i] = f2bf(W[(((size_t)c * 96 + co) * 2 + p) * 2 + q]);
  } else if (tid < NA2 + NUN + NGR){
    int i = tid - NA2 - NUN;
    int side = i / 18432, r = i % 18432;
    int m = r / 96, k = r % 96;
    const float* W = side ? cgw : rgw;       // (96,192) row-major
    Agr[i] = f2bf(W[k * 192 + m]);
  } else if (tid < NA2 + NUN + NGR + 96){
    int co = tid - NA2 - NUN - NGR;
    bun[co] = runb[co] + cunb[co];
  }
}

// ---------------------------------------------------------------------------
// patch conv as implicit GEMM, v3 = v1 geometry + v2 direct-global A + no pm.
// Block: 128 oc x 64 px (4 ho x 16 wo), 4 waves = 2mw x 2nw, wave 64oc x 32px.
// B staged per kh: [4 rows][35 cols][16 chunks x 16B] = 35840 B (4 blocks/CU).
// A-fragments read directly from global (24.6 KB/(kh,kw) slab, L1-hot).
// Only 2 barriers per kh.  Output: channels-last cl only.
// ---------------------------------------------------------------------------
__global__ __launch_bounds__(256) void k_conv(const unsigned short* __restrict__ xt,
    const unsigned short* __restrict__ A2,
    const float* __restrict__ rpb, const float* __restrict__ cpb,
    unsigned short* __restrict__ cl){
  __shared__ char lds[35840];
  int t = threadIdx.x, lane = t & 63;
  int wid = t >> 6, mw = wid >> 1, nw = wid & 1;
  int nt = blockIdx.x;                 // 2048 = b(8) * hq(32) * wq(8)
  int b = nt >> 8, ho0 = ((nt >> 3) & 31) * 4, wo0 = (nt & 7) * 16;
  int M0 = blockIdx.y * 128;

  const unsigned short* Abase = A2 + (size_t)(M0 + mw * 64 + (lane & 15)) * 2400 + (lane >> 4) * 8;

  f32x4 acc[4][2];
  #pragma unroll
  for (int i = 0; i < 4; ++i)
    #pragma unroll
    for (int j = 0; j < 2; ++j) acc[i][j] = (f32x4){0.f, 0.f, 0.f, 0.f};

  for (int kh = 0; kh < 5; ++kh){
    __syncthreads();
    // stage B: 4 rows x 35 cols x 16 chunks, swizzle phys = ch ^ ((col>>1)&7)
    for (int it = 0; it < 9; ++it){
      int i = t + it * 256;
      if (i < 2240){
        int row = i / 560, j = i % 560;
        int col = j >> 4, ch = j & 15;
        size_t src = (((size_t)b * 260 + (2 * ho0 + 2 * row + kh)) * 260 + 2 * wo0 + col) * 128 + ch * 8;
        u32x4 v = *(const u32x4*)&xt[src];
        int chs = ch ^ ((col >> 1) & 7);
        *(u32x4*)(lds + row * 8960 + col * 256 + chs * 16) = v;
      }
    }
    __syncthreads();
    const unsigned short* Akh = Abase + kh * 480;   // + kh*5*96
    #pragma unroll
    for (int kw = 0; kw < 5; ++kw){
      #pragma unroll
      for (int ics = 0; ics < 3; ++ics){
        short8 af[4], bfr[2];
        #pragma unroll
        for (int mf = 0; mf < 4; ++mf)
          af[mf] = *(const short8*)(Akh + (size_t)mf * 16 * 2400 + kw * 96 + ics * 32);
        #pragma unroll
        for (int nf = 0; nf < 2; ++nf){
          int hol = nw * 2 + nf;
          int col = 2 * (lane & 15) + kw;
          int chl = (ics * 4 + (lane >> 4)) ^ ((col >> 1) & 7);
          bfr[nf] = *(const short8*)(lds + hol * 8960 + col * 256 + chl * 16);
        }
        #pragma unroll
        for (int mf = 0; mf < 4; ++mf)
          #pragma unroll
          for (int nf = 0; nf < 2; ++nf)
            acc[mf][nf] = __builtin_amdgcn_mfma_f32_16x16x32_bf16(af[mf], bfr[nf], acc[mf][nf], 0, 0, 0);
      }
    }
  }
  // epilogue: bias, stash to LDS, cooperative channels-last write
  __syncthreads();
  unsigned short* S = (unsigned short*)lds;   // [64 px][128 oc] = 16384 B
  #pragma unroll
  for (int mf = 0; mf < 4; ++mf)
    #pragma unroll
    for (int nf = 0; nf < 2; ++nf){
      int hol = nw * 2 + nf, wol = lane & 15;
      #pragma unroll
      for (int j = 0; j < 4; ++j){
        int oc = M0 + mw * 64 + mf * 16 + (lane >> 4) * 4 + j;
        float v = acc[mf][nf][j] + (oc < 384 ? rpb[oc] : cpb[oc - 384]);
        S[(hol * 16 + wol) * 128 + (oc - M0)] = f2bf(v);
      }
    }
  __syncthreads();
  #pragma unroll
  for (int it = 0; it < 4; ++it){
    int i = t + it * 256;               // 0..1023 = 64 px * 16 chunks
    int pxl = i >> 4, ch = i & 15;
    int ho = ho0 + (pxl >> 4), wo = wo0 + (pxl & 15);
    u32x4 v = *(const u32x4*)&S[pxl * 128 + ch * 8];
    *(u32x4*)&cl[(((size_t)b * 128 + ho) * 128 + wo) * 768 + M0 + ch * 8] = v;
  }
}

// ---------------------------------------------------------------------------
// positional grouped conv 3x3 (groups of 4ch), now reading channels-last cl.
// Block: (b, 48-ch slab, 8hp x 32wp).  si kept [48 ch][10 r][34 c].
// ---------------------------------------------------------------------------
__global__ __launch_bounds__(256) void k_pe(const unsigned short* __restrict__ cl,
    const float* __restrict__ rpew, const float* __restrict__ cpew,
    const float* __restrict__ rpeb, const float* __restrict__ cpeb,
    unsigned short* __restrict__ sum){
  __shared__ unsigned short si[48 * 340];  // [48 ch][10 r][34 c]
  __shared__ float sw[48 * 36];
  __shared__ float sb[48];
  int bid = blockIdx.x;                    // 8*16*16*4
  int wq = bid & 3, hq = (bid >> 2) & 15, slab = (bid >> 6) & 15, b = bid >> 10;
  int ch0 = slab * 48, hp0 = hq * 8, wp0 = wq * 32;
  int t = threadIdx.x;
  for (int i = t; i < 48 * 36; i += 256){
    int ocl = i / 36, r = i % 36;
    int oc = ch0 + ocl;
    const float* W = oc < 384 ? rpew : cpew;
    int o = oc < 384 ? oc : oc - 384;
    sw[i] = W[(size_t)o * 36 + r];
  }
  if (t < 48){
    int oc = ch0 + t;
    sb[t] = oc < 384 ? rpeb[oc] : cpeb[oc - 384];
  }
  for (int i = t; i < 340 * 48; i += 256){   // pixel-major: 48ch contiguous
    int pix = i / 48, c = i % 48;
    int r2 = pix / 34, cc = pix % 34;
    int hp = hp0 - 1 + r2, wp = wp0 - 1 + cc;
    unsigned short v = 0;
    if (hp >= 0 && hp < 128 && wp >= 0 && wp < 128)
      v = cl[((size_t)b * 16384 + hp * 128 + wp) * 768 + ch0 + c];
    si[c * 340 + pix] = v;
  }
  __syncthreads();
  int hpl = t >> 5, wpl = t & 31;
  unsigned int outp[24];
  #pragma unroll
  for (int g = 0; g < 12; ++g){
    float win[36];
    #pragma unroll
    for (int ii = 0; ii < 4; ++ii)
      #pragma unroll
      for (int dh = 0; dh < 3; ++dh)
        #pragma unroll
        for (int dw = 0; dw < 3; ++dw)
          win[ii * 9 + dh * 3 + dw] = bf2f(si[(g * 4 + ii) * 340 + (hpl + dh) * 34 + (wpl + dw)]);
    float o[4];
    #pragma unroll
    for (int ol = 0; ol < 4; ++ol){
      int ocl = g * 4 + ol;
      float a = sb[ocl];
      const float* wp_ = &sw[ocl * 36];
      #pragma unroll
      for (int u = 0; u < 36; ++u) a = fmaf(wp_[u], win[u], a);
      o[ol] = a;
    }
    outp[g * 2]     = (unsigned)f2bf(o[0]) | ((unsigned)f2bf(o[1]) << 16);
    outp[g * 2 + 1] = (unsigned)f2bf(o[2]) | ((unsigned)f2bf(o[3]) << 16);
  }
  size_t obase = (((size_t)b * 128 + hp0 + hpl) * 128 + wp0 + wpl) * 768 + ch0;
  #pragma unroll
  for (int c6 = 0; c6 < 6; ++c6){
    u32x4 v = { outp[c6 * 4], outp[c6 * 4 + 1], outp[c6 * 4 + 2], outp[c6 * 4 + 3] };
    *(u32x4*)&sum[obase + c6 * 8] = v;
  }
}

// ---------------------------------------------------------------------------
// hg GEMM (one side per launch), validated round 5.
// ---------------------------------------------------------------------------
__global__ __launch_bounds__(256) void k_hg(const unsigned short* __restrict__ cl,
    const unsigned short* __restrict__ Agr, unsigned short* __restrict__ hg,
    int side){
  __shared__ char lds[46592];             // A [96][208B]=19968 | B [128][208B]
  int t = threadIdx.x, lane = t & 63, wid = t >> 6;
  int head = blockIdx.z;
  int M0 = blockIdx.y * 96;
  size_t N0 = (size_t)blockIdx.x * 128;
  for (int i = t; i < 1152; i += 256){
    int m = i / 12, c = i % 12;
    u32x4 v = *(const u32x4*)&Agr[((size_t)side * 192 + M0 + m) * 96 + c * 8];
    *(u32x4*)(lds + m * 208 + c * 16) = v;
  }
  for (int i = t; i < 1536; i += 256){
    int px = i / 12, c = i % 12;
    u32x4 v = *(const u32x4*)&cl[(N0 + px) * 768 + side * 384 + head * 96 + c * 8];
    *(u32x4*)(lds + 19968 + px * 208 + c * 16) = v;
  }
  __syncthreads();
  f32x4 acc[6][2];
  #pragma unroll
  for (int i = 0; i < 6; ++i)
    #pragma unroll
    for (int j = 0; j < 2; ++j) acc[i][j] = (f32x4){0.f, 0.f, 0.f, 0.f};
  #pragma unroll
  for (int ks = 0; ks < 3; ++ks){
    short8 af[6], bfr[2];
    #pragma unroll
    for (int mf = 0; mf < 6; ++mf)
      af[mf] = *(const short8*)(lds + (mf * 16 + (lane & 15)) * 208 + ks * 64 + (lane >> 4) * 16);
    #pragma unroll
    for (int nf = 0; nf < 2; ++nf)
      bfr[nf] = *(const short8*)(lds + 19968 + (wid * 32 + nf * 16 + (lane & 15)) * 208 + ks * 64 + (lane >> 4) * 16);
    #pragma unroll
    for (int mf = 0; mf < 6; ++mf)
      #pragma unroll
      for (int nf = 0; nf < 2; ++nf)
        acc[mf][nf] = __builtin_amdgcn_mfma_f32_16x16x32_bf16(af[mf], bfr[nf], acc[mf][nf], 0, 0, 0);
  }
  #pragma unroll
  for (int mf = 0; mf < 6; ++mf)
    #pragma unroll
    for (int nf = 0; nf < 2; ++nf){
      int m = M0 + mf * 16 + ((lane >> 4) << 2);
      size_t px = N0 + wid * 32 + nf * 16 + (lane & 15);
      int b = (int)(px >> 14); size_t pxl = px & 16383;
      size_t base = (((size_t)b * 4 + head) * 16384 + pxl) * 192 + m;
      unsigned p0 = (unsigned)f2bf(acc[mf][nf][0]) | ((unsigned)f2bf(acc[mf][nf][1]) << 16);
      unsigned p1 = (unsigned)f2bf(acc[mf][nf][2]) | ((unsigned)f2bf(acc[mf][nf][3]) << 16);
      unsigned long long pp = (unsigned long long)p0 | ((unsigned long long)p1 << 32);
      *(unsigned long long*)&hg[base] = pp;
    }
}

// ---------------------------------------------------------------------------
// minGRU recurrence (one side per launch), validated round 5.
// ---------------------------------------------------------------------------
__global__ __launch_bounds__(192) void k_scan2(const unsigned short* __restrict__ hg,
                                               unsigned short* __restrict__ sum,
                                               int side){
  int bid = blockIdx.x;
  int xq = bid & 63, head = (bid >> 6) & 3, b = bid >> 8;
  int t = threadIdx.x;
  int d = t % 96, xl = t / 96;
  int x = xq * 2 + xl;
  const unsigned short* hb = &hg[(((size_t)b * 4 + head) * 16384) * 192];
  float h = 0.f;
  for (int step = 0; step < 128; ++step){
    int pxl = side ? (x * 128 + step) : (step * 128 + x);
    float hid = bf2f(hb[(size_t)pxl * 192 + d]);
    float gat = bf2f(hb[(size_t)pxl * 192 + 96 + d]);
    float z  = 1.f / (1.f + __expf(-gat));
    float th = hid >= 0.f ? hid + 0.5f : 1.f / (1.f + __expf(-hid));
    h += z * (th - h);
    size_t o = ((size_t)b * 16384 + pxl) * 768 + side * 384 + head * 96 + d;
    sum[o] = f2bf(bf2f(sum[o]) + h);
  }
}

// ---------------------------------------------------------------------------
// unpatch (validated round 4).
// ---------------------------------------------------------------------------
__global__ __launch_bounds__(256) void k_unpatch(const unsigned short* __restrict__ sum,
    const unsigned short* __restrict__ Aun, const float* __restrict__ bun,
    float* __restrict__ out){
  __shared__ char lds[53248];            // A [128][208B] | B [128][208B]
  int t = threadIdx.x, lane = t & 63;
  int wid = t >> 6, mw = wid >> 1, nw = wid & 1;
  int M0 = blockIdx.y * 128;
  size_t N0 = (size_t)blockIdx.x * 128;
  f32x4 acc[4][4];
  #pragma unroll
  for (int i = 0; i < 4; ++i)
    #pragma unroll
    for (int j = 0; j < 4; ++j) acc[i][j] = (f32x4){0.f, 0.f, 0.f, 0.f};
  for (int kc = 0; kc < 8; ++kc){
    __syncthreads();
    for (int i = t; i < 1536; i += 256){
      int m = i / 12, c = i % 12;
      u32x4 v = *(const u32x4*)&Aun[(size_t)(M0 + m) * 768 + kc * 96 + c * 8];
      *(u32x4*)(lds + m * 208 + c * 16) = v;
    }
    for (int i = t; i < 1536; i += 256){
      int px = i / 12, c = i % 12;
      u32x4 v = *(const u32x4*)&sum[(N0 + px) * 768 + kc * 96 + c * 8];
      *(u32x4*)(lds + 26624 + px * 208 + c * 16) = v;
    }
    __syncthreads();
    #pragma unroll
    for (int ks = 0; ks < 3; ++ks){
      short8 af[4], bfr[4];
      #pragma unroll
      for (int mf = 0; mf < 4; ++mf)
        af[mf] = *(const short8*)(lds + (mw * 64 + mf * 16 + (lane & 15)) * 208 + ks * 64 + (lane >> 4) * 16);
      #pragma unroll
      for (int nf = 0; nf < 4; ++nf)
        bfr[nf] = *(const short8*)(lds + 26624 + (nw * 64 + nf * 16 + (lane & 15)) * 208 + ks * 64 + (lane >> 4) * 16);
      #pragma unroll
      for (int mf = 0; mf < 4; ++mf)
        #pragma unroll
        for (int nf = 0; nf < 4; ++nf)
          acc[mf][nf] = __builtin_amdgcn_mfma_f32_16x16x32_bf16(af[mf], bfr[nf], acc[mf][nf], 0, 0, 0);
    }
  }
  #pragma unroll
  for (int mf = 0; mf < 4; ++mf)
    #pragma unroll
    for (int nf = 0; nf < 4; ++nf)
      #pragma unroll
      for (int j = 0; j < 4; ++j){
        int m = M0 + mw * 64 + mf * 16 + (lane >> 4) * 4 + j;
        int co = m >> 2, p = (m >> 1) & 1, q = m & 1;
        size_t px = N0 + nw * 64 + nf * 16 + (lane & 15);
        int b = (int)(px >> 14); int pxl = (int)(px & 16383);
        int hp = pxl >> 7, wp = pxl & 127;
        out[(((size_t)b * 96 + co) * 256 + 2 * hp + p) * 256 + 2 * wp + q] = acc[mf][nf][j] + bun[co];
      }
}

// ---------------------------------------------------------------------------
extern "C" void kernel_launch(void* const* d_in, const int* in_sizes, int n_in,
                              void* d_out, int out_size, void* d_ws, size_t ws_size,
                              hipStream_t stream){
  (void)in_sizes; (void)n_in; (void)out_size;
  const float* x    = (const float*)d_in[0];
  const float* rpw  = (const float*)d_in[1];
  const float* rpb  = (const float*)d_in[2];
  const float* cpw  = (const float*)d_in[3];
  const float* cpb  = (const float*)d_in[4];
  const float* rpew = (const float*)d_in[5];
  const float* rpeb = (const float*)d_in[6];
  const float* cpew = (const float*)d_in[7];
  const float* cpeb = (const float*)d_in[8];
  const float* runw = (const float*)d_in[9];
  const float* runb = (const float*)d_in[10];
  const float* cunw = (const float*)d_in[11];
  const float* cunb = (const float*)d_in[12];
  const float* rgw  = (const float*)d_in[13];
  const float* cgw  = (const float*)d_in[14];

  char* ws = (char*)d_ws;
  const size_t SZ_XT   = (size_t)8 * 260 * 260 * 128 * 2;   // 138,444,800
  const size_t OFF_A2  = SZ_XT;
  const size_t SZ_A2   = (size_t)768 * 2400 * 2;
  const size_t OFF_AUN = OFF_A2 + SZ_A2;
  const size_t SZ_AUN  = (size_t)384 * 768 * 2;
  const size_t OFF_AGR = OFF_AUN + SZ_AUN;
  const size_t SZ_AGR  = (size_t)2 * 192 * 96 * 2;
  const size_t OFF_BUN = OFF_AGR + SZ_AGR;
  const size_t OFF_HG  = ((OFF_BUN + 384) + 255) & ~(size_t)255;
  const size_t SZ_PL   = (size_t)8 * 768 * 128 * 128 * 2;   // 201,326,592
  const size_t OFF_CL  = OFF_HG + SZ_PL;
  const size_t OFF_SUM = OFF_CL + SZ_PL;
  const size_t NEED    = OFF_SUM + SZ_PL;                   // ~747 MB
  if (ws_size < NEED){
    fprintf(stderr, "kernel_launch: ws_size %zu < needed %zu\n", ws_size, NEED);
    return;
  }
  unsigned short* xt  = (unsigned short*)(ws);
  unsigned short* A2  = (unsigned short*)(ws + OFF_A2);
  unsigned short* Aun = (unsigned short*)(ws + OFF_AUN);
  unsigned short* Agr = (unsigned short*)(ws + OFF_AGR);
  float*          bun = (float*)(ws + OFF_BUN);
  unsigned short* hg  = (unsigned short*)(ws + OFF_HG);  // per-side hg scratch
  unsigned short* cl  = (unsigned short*)(ws + OFF_CL);
  unsigned short* sum = (unsigned short*)(ws + OFF_SUM);
  float* out = (float*)d_out;

  hipMemsetAsync(xt, 0, SZ_XT, stream);
  k_xt  <<<dim3(8192),       dim3(256), 0, stream>>>(x, xt);
  k_pack<<<dim3(8497),       dim3(256), 0, stream>>>(rpw, cpw, runw, cunw, runb, cunb, rgw, cgw, A2, Aun, Agr, bun);
  k_conv<<<dim3(2048, 6),    dim3(256), 0, stream>>>(xt, A2, rpb, cpb, cl);
  k_pe  <<<dim3(8192),       dim3(256), 0, stream>>>(cl, rpew, cpew, rpeb, cpeb, sum);
  k_hg   <<<dim3(1024, 2, 4),dim3(256), 0, stream>>>(cl, Agr, hg, 0);
  k_scan2<<<dim3(2048),      dim3(192), 0, stream>>>(hg, sum, 0);
  k_hg   <<<dim3(1024, 2, 4),dim3(256), 0, stream>>>(cl, Agr, hg, 1);
  k_scan2<<<dim3(2048),      dim3(192), 0, stream>>>(hg, sum, 1);
  k_unpatch<<<dim3(1024, 3), dim3(256), 0, stream>>>(sum, Aun, bun, out);
}

// Round 8
// 2367.005 us; speedup vs baseline: 1.3561x; 1.1313x over previous
//
#include <hip/hip_runtime.h>
#include <stdint.h>
#include <stdio.h>

typedef __attribute__((ext_vector_type(8))) short short8;
typedef __attribute__((ext_vector_type(4))) float f32x4;
typedef __attribute__((ext_vector_type(4))) unsigned int u32x4;

#define DEV static __device__ __forceinline__

DEV unsigned short f2bf(float f){
  unsigned u = __float_as_uint(f);
  u += 0x7FFFu + ((u >> 16) & 1u);          // RNE
  return (unsigned short)(u >> 16);
}
DEV float bf2f(unsigned short h){ return __uint_as_float(((unsigned)h) << 16); }

// ---------------------------------------------------------------------------
// x (8,96,256,256) f32  ->  xt (8,260,260,128) bf16 channels-last with halo=2
// ---------------------------------------------------------------------------
__global__ __launch_bounds__(256) void k_xt(const float* __restrict__ x,
                                            unsigned short* __restrict__ xt){
  int bid = blockIdx.x;                 // 8*256*4
  int wq = bid & 3, h = (bid >> 2) & 255, b = bid >> 10;
  int w0 = wq * 64;
  __shared__ unsigned short s[64 * 104];
  int t = threadIdx.x;
  int wl = t & 63, cq = t >> 6;         // cq 0..3
  const float* xp = x + ((size_t)b * 96 * 256 + h) * 256 + w0 + wl;
  #pragma unroll
  for (int i = 0; i < 24; ++i){
    int c = cq + i * 4;                 // 0..95
    s[wl * 104 + c] = f2bf(xp[(size_t)c * 65536]);
  }
  __syncthreads();
  unsigned short* dst = xt + (((size_t)b * 260 + h + 2) * 260 + (w0 + 2)) * 128;
  #pragma unroll
  for (int p = 0; p < 3; ++p){
    int i = t + p * 256;                // 0..767 = 64 w * 12 chunks
    int w = i / 12, ch = i % 12;
    u32x4 v = *(const u32x4*)&s[w * 104 + ch * 8];
    *(u32x4*)&dst[(size_t)w * 128 + ch * 8] = v;
  }
}

// ---------------------------------------------------------------------------
// weight repack (bf16):
//  A2  [768][ (kh*5+kw)*96 + ic ]   patch-conv weights (r then c)
//  Aun [m=co*4+p*2+q][ci 0..767]    unpatch weights
//  Agr [side][m 0..191][k 0..95]    gru weights transposed
//  bun [96] f32 = r_un_b + c_un_b
// ---------------------------------------------------------------------------
__global__ __launch_bounds__(256) void k_pack(const float* __restrict__ rpw, const float* __restrict__ cpw,
    const float* __restrict__ runw, const float* __restrict__ cunw,
    const float* __restrict__ runb, const float* __restrict__ cunb,
    const float* __restrict__ rgw,  const float* __restrict__ cgw,
    unsigned short* __restrict__ A2, unsigned short* __restrict__ Aun,
    unsigned short* __restrict__ Agr, float* __restrict__ bun){
  int tid = blockIdx.x * 256 + threadIdx.x;
  const int NA2 = 768 * 2400, NUN = 384 * 768, NGR = 2 * 192 * 96;
  if (tid < NA2){
    int oc = tid / 2400, r = tid % 2400;
    int kh = r / 480, kw = (r / 96) % 5, ic = r % 96;
    const float* W = oc < 384 ? rpw : cpw;
    int o = oc < 384 ? oc : oc - 384;
    A2[tid] = f2bf(W[(((size_t)o * 96 + ic) * 5 + kh) * 5 + kw]);
  } else if (tid < NA2 + NUN){
    int i = tid - NA2;
    int m = i / 768, ci = i % 768;
    int co = m >> 2, p = (m >> 1) & 1, q = m & 1;
    const float* W = ci < 384 ? runw : cunw;
    int c = ci < 384 ? ci : ci - 384;
    Aun[i] = f2bf(W[(((size_t)c * 96 + co) * 2 + p) * 2 + q]);
  } else if (tid < NA2 + NUN + NGR){
    int i = tid - NA2 - NUN;
    int side = i / 18432, r = i % 18432;
    int m = r / 96, k = r % 96;
    const float* W = side ? cgw : rgw;       // (96,192) row-major
    Agr[i] = f2bf(W[k * 192 + m]);
  } else if (tid < NA2 + NUN + NGR + 96){
    int co = tid - NA2 - NUN - NGR;
    bun[co] = runb[co] + cunb[co];
  }
}

// ---------------------------------------------------------------------------
// patch conv as implicit GEMM, v5.
// Block 128oc x 64px (4ho x 16wo), 4 waves (2mw x 2nw), wave 64oc x 32px.
// A in LDS, DOUBLE-BUFFERED per (kh,kw) slab (25 slabs), async-staged:
//   next slab's A issued global->reg BEFORE compute, ds_written AFTER barrier.
// B in LDS per kh, 12 real chunks only (ic 0..95), rotation swizzle
//   phys_ch = (ch + (col>>1)) % 12; next kh's B reg-issued during kw==4 slab.
// LDS = 2*26624 (A) + 26880 (B) = 80128 -> 2 blocks/CU (8 waves/CU).
// 2 barriers per slab; global latency hidden under 24 MFMA/slab.
// ---------------------------------------------------------------------------
__global__ __launch_bounds__(256) void k_conv(const unsigned short* __restrict__ xt,
    const unsigned short* __restrict__ A2,
    const float* __restrict__ rpb, const float* __restrict__ cpb,
    unsigned short* __restrict__ cl){
  __shared__ char lds[80128];
  const int BOFF = 53248;               // B region offset
  int t = threadIdx.x, lane = t & 63;
  int wid = t >> 6, mw = wid >> 1, nw = wid & 1;
  int wl = lane & 15, cg = lane >> 4;
  int nt = blockIdx.x;                  // 2048 = b(8) * hq(32) * wq(8)
  int b = nt >> 8, ho0 = ((nt >> 3) & 31) * 4, wo0 = (nt & 7) * 16;
  int M0 = blockIdx.y * 128;

  // A staging role: oc = t>>1 (0..127), half = t&1 (48 elems each)
  int a_oc = t >> 1, a_half = t & 1;
  const unsigned short* Aoc = A2 + (size_t)(M0 + a_oc) * 2400 + a_half * 48;
  char* Adst = lds + a_oc * 208 + a_half * 96;

  f32x4 acc[4][2];
  #pragma unroll
  for (int i = 0; i < 4; ++i)
    #pragma unroll
    for (int j = 0; j < 2; ++j) acc[i][j] = (f32x4){0.f, 0.f, 0.f, 0.f};

  u32x4 aR[6], bR[7];
  // ---- prologue: slab (0,0) A + B(kh=0) ----
  #pragma unroll
  for (int c = 0; c < 6; ++c) aR[c] = *(const u32x4*)(Aoc + c * 8);
  #pragma unroll
  for (int it = 0; it < 7; ++it){
    int i = t + it * 256;
    if (i < 1680){
      int row = i / 420, j = i % 420, col = j / 12, ch = j % 12;
      bR[it] = *(const u32x4*)&xt[(((size_t)b * 260 + 2 * ho0 + 2 * row) * 260 + 2 * wo0 + col) * 128 + ch * 8];
    }
  }
  #pragma unroll
  for (int c = 0; c < 6; ++c) *(u32x4*)(Adst + c * 16) = aR[c];
  #pragma unroll
  for (int it = 0; it < 7; ++it){
    int i = t + it * 256;
    if (i < 1680){
      int row = i / 420, j = i % 420, col = j / 12, ch = j % 12;
      *(u32x4*)(lds + BOFF + row * 6720 + col * 192 + ((ch + (col >> 1)) % 12) * 16) = bR[it];
    }
  }
  __syncthreads();

  int cur = 0;
  for (int kh = 0; kh < 5; ++kh){
    for (int kw = 0; kw < 5; ++kw){
      bool last = (kh == 4 && kw == 4);
      bool khb  = (kw == 4 && kh < 4);
      // issue next-slab A prefetch (global -> regs)
      if (!last){
        int nkh = kh + (kw == 4 ? 1 : 0), nkw = (kw == 4 ? 0 : kw + 1);
        const unsigned short* As = Aoc + (nkh * 5 + nkw) * 96;
        #pragma unroll
        for (int c = 0; c < 6; ++c) aR[c] = *(const u32x4*)(As + c * 8);
      }
      // issue next-kh B prefetch
      if (khb){
        #pragma unroll
        for (int it = 0; it < 7; ++it){
          int i = t + it * 256;
          if (i < 1680){
            int row = i / 420, j = i % 420, col = j / 12, ch = j % 12;
            bR[it] = *(const u32x4*)&xt[(((size_t)b * 260 + 2 * ho0 + 2 * row + kh + 1) * 260 + 2 * wo0 + col) * 128 + ch * 8];
          }
        }
      }
      // ---- compute slab (kh,kw) from A[cur], B ----
      {
        char* Ab = lds + cur * 26624;
        int col = 2 * wl + kw;
        int r0 = cg + wl + (kw >> 1);          // (col>>1)+cg = wl + (kw>>1) + cg
        r0 = r0 >= 12 ? r0 - 12 : r0;          // base rotation, ics=0
        #pragma unroll
        for (int ics = 0; ics < 3; ++ics){
          int phys = r0 + ics * 4;
          phys = phys >= 12 ? phys - 12 : phys;
          short8 af[4], bfr[2];
          #pragma unroll
          for (int mf = 0; mf < 4; ++mf)
            af[mf] = *(const short8*)(Ab + (mw * 64 + mf * 16 + wl) * 208 + ics * 64 + cg * 16);
          #pragma unroll
          for (int nf = 0; nf < 2; ++nf)
            bfr[nf] = *(const short8*)(lds + BOFF + (nw * 2 + nf) * 6720 + col * 192 + phys * 16);
          #pragma unroll
          for (int mf = 0; mf < 4; ++mf)
            #pragma unroll
            for (int nf = 0; nf < 2; ++nf)
              acc[mf][nf] = __builtin_amdgcn_mfma_f32_16x16x32_bf16(af[mf], bfr[nf], acc[mf][nf], 0, 0, 0);
        }
      }
      __syncthreads();                  // all waves done reading A[cur^1]/B(kh)
      if (!last){
        #pragma unroll
        for (int c = 0; c < 6; ++c) *(u32x4*)(Adst + (cur ^ 1) * 26624 + c * 16) = aR[c];
        if (khb){
          #pragma unroll
          for (int it = 0; it < 7; ++it){
            int i = t + it * 256;
            if (i < 1680){
              int row = i / 420, j = i % 420, col = j / 12, ch = j % 12;
              *(u32x4*)(lds + BOFF + row * 6720 + col * 192 + ((ch + (col >> 1)) % 12) * 16) = bR[it];
            }
          }
        }
      }
      __syncthreads();                  // staged data visible
      cur ^= 1;
    }
  }
  // epilogue: bias, stash to LDS, cooperative channels-last write
  unsigned short* S = (unsigned short*)lds;   // [64 px][128 oc] = 16384 B
  #pragma unroll
  for (int mf = 0; mf < 4; ++mf)
    #pragma unroll
    for (int nf = 0; nf < 2; ++nf){
      int hol = nw * 2 + nf, wol = wl;
      #pragma unroll
      for (int j = 0; j < 4; ++j){
        int oc = M0 + mw * 64 + mf * 16 + cg * 4 + j;
        float v = acc[mf][nf][j] + (oc < 384 ? rpb[oc] : cpb[oc - 384]);
        S[(hol * 16 + wol) * 128 + (oc - M0)] = f2bf(v);
      }
    }
  __syncthreads();
  #pragma unroll
  for (int it = 0; it < 4; ++it){
    int i = t + it * 256;               // 0..1023 = 64 px * 16 chunks
    int pxl = i >> 4, ch = i & 15;
    int ho = ho0 + (pxl >> 4), wo = wo0 + (pxl & 15);
    u32x4 v = *(const u32x4*)&S[pxl * 128 + ch * 8];
    *(u32x4*)&cl[(((size_t)b * 128 + ho) * 128 + wo) * 768 + M0 + ch * 8] = v;
  }
}

// ---------------------------------------------------------------------------
// positional grouped conv 3x3 (groups of 4ch), reading channels-last cl.
// ---------------------------------------------------------------------------
__global__ __launch_bounds__(256) void k_pe(const unsigned short* __restrict__ cl,
    const float* __restrict__ rpew, const float* __restrict__ cpew,
    const float* __restrict__ rpeb, const float* __restrict__ cpeb,
    unsigned short* __restrict__ sum){
  __shared__ unsigned short si[48 * 340];  // [48 ch][10 r][34 c]
  __shared__ float sw[48 * 36];
  __shared__ float sb[48];
  int bid = blockIdx.x;                    // 8*16*16*4
  int wq = bid & 3, hq = (bid >> 2) & 15, slab = (bid >> 6) & 15, b = bid >> 10;
  int ch0 = slab * 48, hp0 = hq * 8, wp0 = wq * 32;
  int t = threadIdx.x;
  for (int i = t; i < 48 * 36; i += 256){
    int ocl = i / 36, r = i % 36;
    int oc = ch0 + ocl;
    const float* W = oc < 384 ? rpew : cpew;
    int o = oc < 384 ? oc : oc - 384;
    sw[i] = W[(size_t)o * 36 + r];
  }
  if (t < 48){
    int oc = ch0 + t;
    sb[t] = oc < 384 ? rpeb[oc] : cpeb[oc - 384];
  }
  for (int i = t; i < 340 * 48; i += 256){   // pixel-major: 48ch contiguous
    int pix = i / 48, c = i % 48;
    int r2 = pix / 34, cc = pix % 34;
    int hp = hp0 - 1 + r2, wp = wp0 - 1 + cc;
    unsigned short v = 0;
    if (hp >= 0 && hp < 128 && wp >= 0 && wp < 128)
      v = cl[((size_t)b * 16384 + hp * 128 + wp) * 768 + ch0 + c];
    si[c * 340 + pix] = v;
  }
  __syncthreads();
  int hpl = t >> 5, wpl = t & 31;
  unsigned int outp[24];
  #pragma unroll
  for (int g = 0; g < 12; ++g){
    float win[36];
    #pragma unroll
    for (int ii = 0; ii < 4; ++ii)
      #pragma unroll
      for (int dh = 0; dh < 3; ++dh)
        #pragma unroll
        for (int dw = 0; dw < 3; ++dw)
          win[ii * 9 + dh * 3 + dw] = bf2f(si[(g * 4 + ii) * 340 + (hpl + dh) * 34 + (wpl + dw)]);
    float o[4];
    #pragma unroll
    for (int ol = 0; ol < 4; ++ol){
      int ocl = g * 4 + ol;
      float a = sb[ocl];
      const float* wp_ = &sw[ocl * 36];
      #pragma unroll
      for (int u = 0; u < 36; ++u) a = fmaf(wp_[u], win[u], a);
      o[ol] = a;
    }
    outp[g * 2]     = (unsigned)f2bf(o[0]) | ((unsigned)f2bf(o[1]) << 16);
    outp[g * 2 + 1] = (unsigned)f2bf(o[2]) | ((unsigned)f2bf(o[3]) << 16);
  }
  size_t obase = (((size_t)b * 128 + hp0 + hpl) * 128 + wp0 + wpl) * 768 + ch0;
  #pragma unroll
  for (int c6 = 0; c6 < 6; ++c6){
    u32x4 v = { outp[c6 * 4], outp[c6 * 4 + 1], outp[c6 * 4 + 2], outp[c6 * 4 + 3] };
    *(u32x4*)&sum[obase + c6 * 8] = v;
  }
}

// ---------------------------------------------------------------------------
// hg GEMM (one side per launch), validated round 5.
// ---------------------------------------------------------------------------
__global__ __launch_bounds__(256) void k_hg(const unsigned short* __restrict__ cl,
    const unsigned short* __restrict__ Agr, unsigned short* __restrict__ hg,
    int side){
  __shared__ char lds[46592];             // A [96][208B]=19968 | B [128][208B]
  int t = threadIdx.x, lane = t & 63, wid = t >> 6;
  int head = blockIdx.z;
  int M0 = blockIdx.y * 96;
  size_t N0 = (size_t)blockIdx.x * 128;
  for (int i = t; i < 1152; i += 256){
    int m = i / 12, c = i % 12;
    u32x4 v = *(const u32x4*)&Agr[((size_t)side * 192 + M0 + m) * 96 + c * 8];
    *(u32x4*)(lds + m * 208 + c * 16) = v;
  }
  for (int i = t; i < 1536; i += 256){
    int px = i / 12, c = i % 12;
    u32x4 v = *(const u32x4*)&cl[(N0 + px) * 768 + side * 384 + head * 96 + c * 8];
    *(u32x4*)(lds + 19968 + px * 208 + c * 16) = v;
  }
  __syncthreads();
  f32x4 acc[6][2];
  #pragma unroll
  for (int i = 0; i < 6; ++i)
    #pragma unroll
    for (int j = 0; j < 2; ++j) acc[i][j] = (f32x4){0.f, 0.f, 0.f, 0.f};
  #pragma unroll
  for (int ks = 0; ks < 3; ++ks){
    short8 af[6], bfr[2];
    #pragma unroll
    for (int mf = 0; mf < 6; ++mf)
      af[mf] = *(const short8*)(lds + (mf * 16 + (lane & 15)) * 208 + ks * 64 + (lane >> 4) * 16);
    #pragma unroll
    for (int nf = 0; nf < 2; ++nf)
      bfr[nf] = *(const short8*)(lds + 19968 + (wid * 32 + nf * 16 + (lane & 15)) * 208 + ks * 64 + (lane >> 4) * 16);
    #pragma unroll
    for (int mf = 0; mf < 6; ++mf)
      #pragma unroll
      for (int nf = 0; nf < 2; ++nf)
        acc[mf][nf] = __builtin_amdgcn_mfma_f32_16x16x32_bf16(af[mf], bfr[nf], acc[mf][nf], 0, 0, 0);
  }
  #pragma unroll
  for (int mf = 0; mf < 6; ++mf)
    #pragma unroll
    for (int nf = 0; nf < 2; ++nf){
      int m = M0 + mf * 16 + ((lane >> 4) << 2);
      size_t px = N0 + wid * 32 + nf * 16 + (lane & 15);
      int b = (int)(px >> 14); size_t pxl = px & 16383;
      size_t base = (((size_t)b * 4 + head) * 16384 + pxl) * 192 + m;
      unsigned p0 = (unsigned)f2bf(acc[mf][nf][0]) | ((unsigned)f2bf(acc[mf][nf][1]) << 16);
      unsigned p1 = (unsigned)f2bf(acc[mf][nf][2]) | ((unsigned)f2bf(acc[mf][nf][3]) << 16);
      unsigned long long pp = (unsigned long long)p0 | ((unsigned long long)p1 << 32);
      *(unsigned long long*)&hg[base] = pp;
    }
}

// ---------------------------------------------------------------------------
// minGRU recurrence (one side per launch), validated round 5.
// ---------------------------------------------------------------------------
__global__ __launch_bounds__(192) void k_scan2(const unsigned short* __restrict__ hg,
                                               unsigned short* __restrict__ sum,
                                               int side){
  int bid = blockIdx.x;
  int xq = bid & 63, head = (bid >> 6) & 3, b = bid >> 8;
  int t = threadIdx.x;
  int d = t % 96, xl = t / 96;
  int x = xq * 2 + xl;
  const unsigned short* hb = &hg[(((size_t)b * 4 + head) * 16384) * 192];
  float h = 0.f;
  for (int step = 0; step < 128; ++step){
    int pxl = side ? (x * 128 + step) : (step * 128 + x);
    float hid = bf2f(hb[(size_t)pxl * 192 + d]);
    float gat = bf2f(hb[(size_t)pxl * 192 + 96 + d]);
    float z  = 1.f / (1.f + __expf(-gat));
    float th = hid >= 0.f ? hid + 0.5f : 1.f / (1.f + __expf(-hid));
    h += z * (th - h);
    size_t o = ((size_t)b * 16384 + pxl) * 768 + side * 384 + head * 96 + d;
    sum[o] = f2bf(bf2f(sum[o]) + h);
  }
}

// ---------------------------------------------------------------------------
// unpatch (validated round 4).
// ---------------------------------------------------------------------------
__global__ __launch_bounds__(256) void k_unpatch(const unsigned short* __restrict__ sum,
    const unsigned short* __restrict__ Aun, const float* __restrict__ bun,
    float* __restrict__ out){
  __shared__ char lds[53248];            // A [128][208B] | B [128][208B]
  int t = threadIdx.x, lane = t & 63;
  int wid = t >> 6, mw = wid >> 1, nw = wid & 1;
  int M0 = blockIdx.y * 128;
  size_t N0 = (size_t)blockIdx.x * 128;
  f32x4 acc[4][4];
  #pragma unroll
  for (int i = 0; i < 4; ++i)
    #pragma unroll
    for (int j = 0; j < 4; ++j) acc[i][j] = (f32x4){0.f, 0.f, 0.f, 0.f};
  for (int kc = 0; kc < 8; ++kc){
    __syncthreads();
    for (int i = t; i < 1536; i += 256){
      int m = i / 12, c = i % 12;
      u32x4 v = *(const u32x4*)&Aun[(size_t)(M0 + m) * 768 + kc * 96 + c * 8];
      *(u32x4*)(lds + m * 208 + c * 16) = v;
    }
    for (int i = t; i < 1536; i += 256){
      int px = i / 12, c = i % 12;
      u32x4 v = *(const u32x4*)&sum[(N0 + px) * 768 + kc * 96 + c * 8];
      *(u32x4*)(lds + 26624 + px * 208 + c * 16) = v;
    }
    __syncthreads();
    #pragma unroll
    for (int ks = 0; ks < 3; ++ks){
      short8 af[4], bfr[4];
      #pragma unroll
      for (int mf = 0; mf < 4; ++mf)
        af[mf] = *(const short8*)(lds + (mw * 64 + mf * 16 + (lane & 15)) * 208 + ks * 64 + (lane >> 4) * 16);
      #pragma unroll
      for (int nf = 0; nf < 4; ++nf)
        bfr[nf] = *(const short8*)(lds + 26624 + (nw * 64 + nf * 16 + (lane & 15)) * 208 + ks * 64 + (lane >> 4) * 16);
      #pragma unroll
      for (int mf = 0; mf < 4; ++mf)
        #pragma unroll
        for (int nf = 0; nf < 4; ++nf)
          acc[mf][nf] = __builtin_amdgcn_mfma_f32_16x16x32_bf16(af[mf], bfr[nf], acc[mf][nf], 0, 0, 0);
    }
  }
  #pragma unroll
  for (int mf = 0; mf < 4; ++mf)
    #pragma unroll
    for (int nf = 0; nf < 4; ++nf)
      #pragma unroll
      for (int j = 0; j < 4; ++j){
        int m = M0 + mw * 64 + mf * 16 + (lane >> 4) * 4 + j;
        int co = m >> 2, p = (m >> 1) & 1, q = m & 1;
        size_t px = N0 + nw * 64 + nf * 16 + (lane & 15);
        int b = (int)(px >> 14); int pxl = (int)(px & 16383);
        int hp = pxl >> 7, wp = pxl & 127;
        out[(((size_t)b * 96 + co) * 256 + 2 * hp + p) * 256 + 2 * wp + q] = acc[mf][nf][j] + bun[co];
      }
}

// ---------------------------------------------------------------------------
extern "C" void kernel_launch(void* const* d_in, const int* in_sizes, int n_in,
                              void* d_out, int out_size, void* d_ws, size_t ws_size,
                              hipStream_t stream){
  (void)in_sizes; (void)n_in; (void)out_size;
  const float* x    = (const float*)d_in[0];
  const float* rpw  = (const float*)d_in[1];
  const float* rpb  = (const float*)d_in[2];
  const float* cpw  = (const float*)d_in[3];
  const float* cpb  = (const float*)d_in[4];
  const float* rpew = (const float*)d_in[5];
  const float* rpeb = (const float*)d_in[6];
  const float* cpew = (const float*)d_in[7];
  const float* cpeb = (const float*)d_in[8];
  const float* runw = (const float*)d_in[9];
  const float* runb = (const float*)d_in[10];
  const float* cunw = (const float*)d_in[11];
  const float* cunb = (const float*)d_in[12];
  const float* rgw  = (const float*)d_in[13];
  const float* cgw  = (const float*)d_in[14];

  char* ws = (char*)d_ws;
  const size_t SZ_XT   = (size_t)8 * 260 * 260 * 128 * 2;   // 138,444,800
  const size_t OFF_A2  = SZ_XT;
  const size_t SZ_A2   = (size_t)768 * 2400 * 2;
  const size_t OFF_AUN = OFF_A2 + SZ_A2;
  const size_t SZ_AUN  = (size_t)384 * 768 * 2;
  const size_t OFF_AGR = OFF_AUN + SZ_AUN;
  const size_t SZ_AGR  = (size_t)2 * 192 * 96 * 2;
  const size_t OFF_BUN = OFF_AGR + SZ_AGR;
  const size_t OFF_HG  = ((OFF_BUN + 384) + 255) & ~(size_t)255;
  const size_t SZ_PL   = (size_t)8 * 768 * 128 * 128 * 2;   // 201,326,592
  const size_t OFF_CL  = OFF_HG + SZ_PL;
  const size_t OFF_SUM = OFF_CL + SZ_PL;
  const size_t NEED    = OFF_SUM + SZ_PL;                   // ~747 MB
  if (ws_size < NEED){
    fprintf(stderr, "kernel_launch: ws_size %zu < needed %zu\n", ws_size, NEED);
    return;
  }
  unsigned short* xt  = (unsigned short*)(ws);
  unsigned short* A2  = (unsigned short*)(ws + OFF_A2);
  unsigned short* Aun = (unsigned short*)(ws + OFF_AUN);
  unsigned short* Agr = (unsigned short*)(ws + OFF_AGR);
  float*          bun = (float*)(ws + OFF_BUN);
  unsigned short* hg  = (unsigned short*)(ws + OFF_HG);  // per-side hg scratch
  unsigned short* cl  = (unsigned short*)(ws + OFF_CL);
  unsigned short* sum = (unsigned short*)(ws + OFF_SUM);
  float* out = (float*)d_out;

  hipMemsetAsync(xt, 0, SZ_XT, stream);
  k_xt  <<<dim3(8192),       dim3(256), 0, stream>>>(x, xt);
  k_pack<<<dim3(8497),       dim3(256), 0, stream>>>(rpw, cpw, runw, cunw, runb, cunb, rgw, cgw, A2, Aun, Agr, bun);
  k_conv<<<dim3(2048, 6),    dim3(256), 0, stream>>>(xt, A2, rpb, cpb, cl);
  k_pe  <<<dim3(8192),       dim3(256), 0, stream>>>(cl, rpew, cpew, rpeb, cpeb, sum);
  k_hg   <<<dim3(1024, 2, 4),dim3(256), 0, stream>>>(cl, Agr, hg, 0);
  k_scan2<<<dim3(2048),      dim3(192), 0, stream>>>(hg, sum, 0);
  k_hg   <<<dim3(1024, 2, 4),dim3(256), 0, stream>>>(cl, Agr, hg, 1);
  k_scan2<<<dim3(2048),      dim3(192), 0, stream>>>(hg, sum, 1);
  k_unpatch<<<dim3(1024, 3), dim3(256), 0, stream>>>(sum, Aun, bun, out);
}